// Round 5
// baseline (2774.707 us; speedup 1.0000x reference)
//
#include <hip/hip_runtime.h>
#include <hip/hip_cooperative_groups.h>

namespace cg = cooperative_groups;

// ---------------- problem constants ----------------
#define L_      8838           // LATENT
#define LP_     9216           // padded row length (bytes per u8 row; floats per LDS vec)
#define MPOW    8              // highest kept power of G (tail ~7e-4 rel -> +0.025 abs)
#define NSLOT   (MPOW + 1)
#define NFULL   3              // passes 1..NFULL read hi+lo; later passes hi-only
#define CT      512            // threads per block (8 waves)
#define HPAIRS  (L_ / 2)       // 4419
#define CABLK   512            // cooperative grid: 2 blocks/CU x 256 CU
#define CAWAVES (CABLK * (CT / 64))   // 4096
#define P0BLK   ((HPAIRS + 7) / 8)    // 553 blocks, 1 pair per wave, no tail

// quantization: q16 = clamp(rn((g + BOFF)/D16), 0, 65535), g = q16*D16 - BOFF
// hi = rn(q16/256) (unbiased hi-only recon), lo = q16 - 256*hi + 128
#define BOFF 6.0e-4f
#define D16  (BOFF / 32768.0f)
#define DHI  (BOFF / 128.0f)           // 256 * D16
#define C2   (BOFF + 128.0f * D16)
#define QS   (32768.0f / BOFF)

typedef float        f32x4 __attribute__((ext_vector_type(4)));
typedef unsigned int u32x4 __attribute__((ext_vector_type(4)));

__device__ __forceinline__ float ubf(unsigned int u, int b) {
    return (float)((u >> (8 * b)) & 255u);   // -> v_cvt_f32_ubyteN
}

__device__ __forceinline__ void stage_vec_f32(const float* __restrict__ gin,
                                              const float* __restrict__ hin,
                                              float* sgf, float* shf)
{
    #pragma unroll
    for (int k = 0; k < LP_ / CT; ++k) {   // 18
        const int j = k * CT + threadIdx.x;
        sgf[j] = (j < L_) ? gin[j] : 0.f;
        shf[j] = (j < L_) ? hin[j] : 0.f;
    }
    __syncthreads();
}

__device__ __forceinline__ void quant4(const float x[4], int j0, int rdiag,
                                       unsigned int& hw, unsigned int& lw)
{
    hw = 0; lw = 0;
    #pragma unroll
    for (int e = 0; e < 4; ++e) {
        const float g = x[e] - ((j0 + e == rdiag) ? 1.f : 0.f);
        int q = __float2int_rn(fmaf(g, QS, 32768.0f));
        q = min(max(q, 0), 65535);
        const int h = min((q + 128) >> 8, 255);
        const int l = min(q - (h << 8) + 128, 255);
        hw |= (unsigned)h << (8 * e);
        lw |= (unsigned)l << (8 * e);
    }
}

// ---------------- fused chain: passes pbeg..pend-1, grid.sync between ----------------
// 512 blocks x 512 thr (exactly co-resident at 2 blocks/CU). Wave w owns rows
// {w, w+4096} (+ scattered extra row 8192+w/6 for w%6==0) on full passes, and
// pair {w} (+ scattered 4096+w/12) on hi-only passes.
__global__ __launch_bounds__(CT, 4)
void chain_all(const unsigned char* __restrict__ GHi,
               const unsigned char* __restrict__ GLo,
               float* __restrict__ gv, float* __restrict__ hv,
               int pbeg, int pend)
{
    cg::grid_group grid = cg::this_grid();
    __shared__ float sgf[LP_], shf[LP_];
    const int lane = threadIdx.x & 63;
    const int w = blockIdx.x * (CT / 64) + (threadIdx.x >> 6);

    for (int p = pbeg; p < pend; ++p) {
        stage_vec_f32(gv + (size_t)p * L_, hv + (size_t)p * L_, sgf, shf);
        float* __restrict__ gout = gv + (size_t)(p + 1) * L_;
        float* __restrict__ hout = hv + (size_t)(p + 1) * L_;

        if (p <= NFULL) {
            // ---- full precision: hi+lo, one row per wave ----
            int rl[3]; int n = 2;
            rl[0] = w; rl[1] = w + CAWAVES; rl[2] = 2 * CAWAVES + w / 6;
            if ((w % 6) == 0 && (w / 6) < (L_ - 2 * CAWAVES)) n = 3;

            u32x4 mh[9], ml[9];
            {
                const unsigned char* RH = GHi + (size_t)rl[0] * LP_ + lane * 16;
                const unsigned char* RL = GLo + (size_t)rl[0] * LP_ + lane * 16;
                #pragma unroll
                for (int c = 0; c < 9; ++c) {
                    mh[c] = *(const u32x4*)(RH + c * 1024);
                    ml[c] = *(const u32x4*)(RL + c * 1024);
                }
            }
            for (int k = 0; k < n; ++k) {
                const bool pf = (k + 1 < n);
                const int nr = pf ? rl[k + 1] : rl[k];
                const unsigned char* RnH = GHi + (size_t)nr * LP_ + lane * 16;
                const unsigned char* RnL = GLo + (size_t)nr * LP_ + lane * 16;
                float ag = 0.f, ah = 0.f;
                #pragma unroll
                for (int c = 0; c < 9; ++c) {
                    const u32x4 uh = mh[c], ul = ml[c];
                    if (pf) {   // wave-uniform branch; prefetch next row into dead regs
                        mh[c] = *(const u32x4*)(RnH + c * 1024);
                        ml[c] = *(const u32x4*)(RnL + c * 1024);
                    }
                    const f32x4* vgp = (const f32x4*)(sgf + c * 1024 + lane * 16);
                    const f32x4* vhp = (const f32x4*)(shf + c * 1024 + lane * 16);
                    #pragma unroll
                    for (int d = 0; d < 4; ++d) {
                        const f32x4 vg = vgp[d], vh = vhp[d];
                        #pragma unroll
                        for (int b = 0; b < 4; ++b) {
                            const float v = fmaf(ubf(uh[d], b), DHI,
                                           fmaf(ubf(ul[d], b), D16, -C2));
                            ag = fmaf(v, vg[b], ag);
                            ah = fmaf(v, vh[b], ah);
                        }
                    }
                }
                #pragma unroll
                for (int o = 32; o; o >>= 1) { ag += __shfl_xor(ag, o); ah += __shfl_xor(ah, o); }
                if (lane == 0) { gout[rl[k]] = ag; hout[rl[k]] = ah; }
            }
        } else {
            // ---- hi-only: int8, one row-PAIR per wave ----
            int pl[2]; int np = 1;
            pl[0] = w; pl[1] = CAWAVES + w / 12;
            if ((w % 12) == 0 && (w / 12) < (HPAIRS - CAWAVES)) np = 2;
            for (int k = 0; k < np; ++k) {
                const int r0 = 2 * pl[k], r1 = r0 + 1;
                const unsigned char* R0 = GHi + (size_t)r0 * LP_ + lane * 16;
                const unsigned char* R1 = R0 + LP_;
                u32x4 m0[9], m1[9];
                #pragma unroll
                for (int c = 0; c < 9; ++c) {
                    m0[c] = *(const u32x4*)(R0 + c * 1024);
                    m1[c] = *(const u32x4*)(R1 + c * 1024);
                }
                float a0g = 0.f, a0h = 0.f, a1g = 0.f, a1h = 0.f;
                #pragma unroll
                for (int c = 0; c < 9; ++c) {
                    const f32x4* vgp = (const f32x4*)(sgf + c * 1024 + lane * 16);
                    const f32x4* vhp = (const f32x4*)(shf + c * 1024 + lane * 16);
                    #pragma unroll
                    for (int d = 0; d < 4; ++d) {
                        const f32x4 vg = vgp[d], vh = vhp[d];
                        #pragma unroll
                        for (int b = 0; b < 4; ++b) {
                            const float v0 = fmaf(ubf(m0[c][d], b), DHI, -BOFF);
                            const float v1 = fmaf(ubf(m1[c][d], b), DHI, -BOFF);
                            a0g = fmaf(v0, vg[b], a0g); a0h = fmaf(v0, vh[b], a0h);
                            a1g = fmaf(v1, vg[b], a1g); a1h = fmaf(v1, vh[b], a1h);
                        }
                    }
                }
                #pragma unroll
                for (int o = 32; o; o >>= 1) {
                    a0g += __shfl_xor(a0g, o); a0h += __shfl_xor(a0h, o);
                    a1g += __shfl_xor(a1g, o); a1h += __shfl_xor(a1h, o);
                }
                if (lane == 0) {
                    gout[r0] = a0g; hout[r0] = a0h;
                    gout[r1] = a1g; hout[r1] = a1h;
                }
            }
        }
        if (p + 1 < pend) grid.sync();   // skipped on per-pass fallback launches
    }
}

// ---------------- pass 0: fp32 A, exact (A-I)*v, fused hi/lo quantized write ----------------
// One row-pair per wave (553 blocks, no tail round). 16B nt loads, unroll-6.
template<bool WRITE_G>
__global__ __launch_bounds__(CT, 4)
void pass0_kernel(const float* __restrict__ A,
                  const float* __restrict__ gin, const float* __restrict__ hin,
                  unsigned char* __restrict__ GHi, unsigned char* __restrict__ GLo,
                  float* __restrict__ gout, float* __restrict__ hout)
{
    __shared__ float sgf[LP_], shf[LP_];
    stage_vec_f32(gin, hin, sgf, shf);
    const int lane = threadIdx.x & 63;
    const int pr = blockIdx.x * (CT / 64) + (threadIdx.x >> 6);
    if (pr >= HPAIRS) return;
    const int r0 = 2 * pr, r1 = r0 + 1;
    const float* __restrict__ A0 = A + (size_t)r0 * L_;
    const float* __restrict__ A1 = A + (size_t)r1 * L_;

    float a00 = 0.f, a01 = 0.f, a10 = 0.f, a11 = 0.f;
    #pragma unroll 6
    for (int it = 0; it < 34; ++it) {        // full 16B iters: up to col 8703
        const int j0 = it * 256 + lane * 4;
        const f32x4 x0 = __builtin_nontemporal_load((const f32x4*)(A0 + j0));
        const f32x4 x1 = __builtin_nontemporal_load((const f32x4*)(A1 + j0));
        if constexpr (WRITE_G) {
            float y0[4] = {x0[0], x0[1], x0[2], x0[3]};
            float y1[4] = {x1[0], x1[1], x1[2], x1[3]};
            unsigned int hw0, lw0, hw1, lw1;
            quant4(y0, j0, r0, hw0, lw0);
            quant4(y1, j0, r1, hw1, lw1);
            *(unsigned int*)(GHi + (size_t)r0 * LP_ + j0) = hw0;
            *(unsigned int*)(GLo + (size_t)r0 * LP_ + j0) = lw0;
            *(unsigned int*)(GHi + (size_t)r1 * LP_ + j0) = hw1;
            *(unsigned int*)(GLo + (size_t)r1 * LP_ + j0) = lw1;
        }
        const f32x4 vg = *(const f32x4*)(sgf + j0);
        const f32x4 vh = *(const f32x4*)(shf + j0);
        #pragma unroll
        for (int e = 0; e < 4; ++e) {
            a00 = fmaf(x0[e], vg[e], a00); a01 = fmaf(x0[e], vh[e], a01);
            a10 = fmaf(x1[e], vg[e], a10); a11 = fmaf(x1[e], vh[e], a11);
        }
    }
    {   // tail iter (cols 8704..8837, guarded; OOB encoded as exact zero)
        const int j0 = 34 * 256 + lane * 4;
        float x0[4], x1[4];
        #pragma unroll
        for (int e = 0; e < 4; ++e) {
            x0[e] = (j0 + e < L_) ? A0[j0 + e] : 0.f;
            x1[e] = (j0 + e < L_) ? A1[j0 + e] : 0.f;
        }
        if constexpr (WRITE_G) {
            unsigned int hw0, lw0, hw1, lw1;
            quant4(x0, j0, r0, hw0, lw0);
            quant4(x1, j0, r1, hw1, lw1);
            *(unsigned int*)(GHi + (size_t)r0 * LP_ + j0) = hw0;
            *(unsigned int*)(GLo + (size_t)r0 * LP_ + j0) = lw0;
            *(unsigned int*)(GHi + (size_t)r1 * LP_ + j0) = hw1;
            *(unsigned int*)(GLo + (size_t)r1 * LP_ + j0) = lw1;
        }
        const f32x4 vg = *(const f32x4*)(sgf + j0);   // zeros beyond L_
        const f32x4 vh = *(const f32x4*)(shf + j0);
        #pragma unroll
        for (int e = 0; e < 4; ++e) {
            a00 = fmaf(x0[e], vg[e], a00); a01 = fmaf(x0[e], vh[e], a01);
            a10 = fmaf(x1[e], vg[e], a10); a11 = fmaf(x1[e], vh[e], a11);
        }
    }
    #pragma unroll
    for (int o = 32; o; o >>= 1) {
        a00 += __shfl_xor(a00, o); a01 += __shfl_xor(a01, o);
        a10 += __shfl_xor(a10, o); a11 += __shfl_xor(a11, o);
    }
    if (lane == 0) {   // subtract exact identity contribution
        gout[r0] = a00 - sgf[r0];
        hout[r0] = a01 - shf[r0];
        gout[r1] = a10 - sgf[r1];
        hout[r1] = a11 - shf[r1];
    }
}

// ---------------- binomial coefficients (fp64) ----------------
__global__ void coeff_kernel(const float* __restrict__ xs,
                             double* __restrict__ s, double* __restrict__ c256)
{
    const int lane = threadIdx.x;        // 64 threads
    const int t0 = lane * 4;
    float xl[8][4];
    #pragma unroll
    for (int b = 0; b < 8; ++b)
        #pragma unroll
        for (int i = 0; i < 4; ++i)
            xl[b][i] = xs[b * 256 + t0 + i];

    double c[4] = {1.0, 1.0, 1.0, 1.0};  // C(255-t, m), m starts at 0
    for (int m = 0; m <= MPOW; ++m) {
        #pragma unroll
        for (int b = 0; b < 8; ++b) {
            double part = c[0] * xl[b][0] + c[1] * xl[b][1]
                        + c[2] * xl[b][2] + c[3] * xl[b][3];
            for (int o = 32; o; o >>= 1) part += __shfl_xor(part, o);
            if (lane == 0) s[m * 8 + b] = part;
        }
        #pragma unroll
        for (int i = 0; i < 4; ++i) {
            double k = (double)(255 - (t0 + i));
            c[i] *= (k - m) / (double)(m + 1);   // -> C(k, m+1); 0 past m=k
        }
    }
    if (lane == 0) {
        double c2 = 1.0;
        for (int m = 0; m <= MPOW; ++m) { c256[m] = c2; c2 = c2 * (256.0 - m) / (double)(m + 1); }
    }
}

// ---------------- combine: p_final[b,i] ----------------
__global__ __launch_bounds__(256)
void combine_kernel(const float* __restrict__ gv, const float* __restrict__ hv,
                    const double* __restrict__ s, const double* __restrict__ c256,
                    float* __restrict__ pfin)
{
    int i = blockIdx.x * 256 + threadIdx.x;
    if (i >= L_) return;
    double acc[8] = {0, 0, 0, 0, 0, 0, 0, 0};
    double hs = 0.0;
    for (int m = 0; m <= MPOW; ++m) {
        double g = (double)gv[(size_t)m * L_ + i];
        double h = (double)hv[(size_t)m * L_ + i];
        hs += c256[m] * h;
        #pragma unroll
        for (int b = 0; b < 8; ++b) acc[b] += s[m * 8 + b] * g;
    }
    #pragma unroll
    for (int b = 0; b < 8; ++b)
        pfin[(size_t)b * L_ + i] = (float)(acc[b] + hs);
}

// ---------------- MLP evaluation ----------------
// weights p: W1[0:64] b1[64:128] W2[128:4224] b2[4224:4288]
//            W3[4288:8384] b3[8384:8448] W4[8448:8832] b4[8832:8838]
__global__ __launch_bounds__(64)
void mlp_kernel(const float* __restrict__ pfin, const float* __restrict__ ts,
                float* __restrict__ out)
{
    const int b = blockIdx.x;
    const int t = blockIdx.y * 64 + threadIdx.x;
    const float* __restrict__ p = pfin + (size_t)b * L_;   // uniform -> s_loads
    const float tv = ts[b * 256 + t];

    float h1[64], h2[64];
    #pragma unroll
    for (int o = 0; o < 64; ++o)
        h1[o] = fmaxf(fmaf(p[o], tv, p[64 + o]), 0.f);
    #pragma unroll
    for (int o = 0; o < 64; ++o) {
        float a0 = p[4224 + o], a1 = 0.f, a2 = 0.f, a3 = 0.f;
        #pragma unroll
        for (int d = 0; d < 64; d += 4) {
            a0 = fmaf(p[128 + o * 64 + d + 0], h1[d + 0], a0);
            a1 = fmaf(p[128 + o * 64 + d + 1], h1[d + 1], a1);
            a2 = fmaf(p[128 + o * 64 + d + 2], h1[d + 2], a2);
            a3 = fmaf(p[128 + o * 64 + d + 3], h1[d + 3], a3);
        }
        h2[o] = fmaxf((a0 + a1) + (a2 + a3), 0.f);
    }
    #pragma unroll
    for (int o = 0; o < 64; ++o) {
        float a0 = p[8384 + o], a1 = 0.f, a2 = 0.f, a3 = 0.f;
        #pragma unroll
        for (int d = 0; d < 64; d += 4) {
            a0 = fmaf(p[4288 + o * 64 + d + 0], h2[d + 0], a0);
            a1 = fmaf(p[4288 + o * 64 + d + 1], h2[d + 1], a1);
            a2 = fmaf(p[4288 + o * 64 + d + 2], h2[d + 2], a2);
            a3 = fmaf(p[4288 + o * 64 + d + 3], h2[d + 3], a3);
        }
        h1[o] = fmaxf((a0 + a1) + (a2 + a3), 0.f);   // reuse as h3
    }
    #pragma unroll
    for (int o = 0; o < 6; ++o) {
        float a0 = p[8832 + o], a1 = 0.f, a2 = 0.f, a3 = 0.f;
        #pragma unroll
        for (int d = 0; d < 64; d += 4) {
            a0 = fmaf(p[8448 + o * 64 + d + 0], h1[d + 0], a0);
            a1 = fmaf(p[8448 + o * 64 + d + 1], h1[d + 1], a1);
            a2 = fmaf(p[8448 + o * 64 + d + 2], h1[d + 2], a2);
            a3 = fmaf(p[8448 + o * 64 + d + 3], h1[d + 3], a3);
        }
        out[((size_t)(b * 256 + t)) * 6 + o] = (a0 + a1) + (a2 + a3);
    }
}

// ---------------- host launcher ----------------
extern "C" void kernel_launch(void* const* d_in, const int* in_sizes, int n_in,
                              void* d_out, int out_size, void* d_ws, size_t ws_size,
                              hipStream_t stream)
{
    const float* xs    = (const float*)d_in[0];  // (8,1,256,1)
    const float* ts    = (const float*)d_in[1];  // (8,256)
    const float* theta = (const float*)d_in[2];  // (8838,)
    const float* A     = (const float*)d_in[3];  // (8838,8838)
    const float* B     = (const float*)d_in[4];  // (8838,1)
    float* out = (float*)d_out;

    const size_t GB1 = (size_t)L_ * LP_;                          // 81,451,008 per array
    const size_t VB  = (size_t)NSLOT * L_ * sizeof(float);
    const size_t SB  = (size_t)NSLOT * 8 * sizeof(double);
    const size_t CB  = 256;                                       // c256 (padded)
    const size_t PB  = (size_t)8 * L_ * sizeof(float);
    const size_t SMALL = 2 * VB + SB + CB + PB;
    const size_t FULL  = 2 * GB1 + SMALL;

    if (ws_size < SMALL) return;   // cannot run; fail loudly via validation
    const bool fat = (ws_size >= FULL);

    char* base = (char*)d_ws;
    unsigned char* GHi = (unsigned char*)base;
    unsigned char* GLo = (unsigned char*)(base + GB1);
    size_t off = fat ? 2 * GB1 : 0;
    float*  gv   = (float*)(base + off);  off += VB;
    float*  hv   = (float*)(base + off);  off += VB;
    double* s    = (double*)(base + off); off += SB;
    double* c256 = (double*)(base + off); off += CB;
    float*  pfin = (float*)(base + off);

    // independent of chain -> launch first
    coeff_kernel<<<1, 64, 0, stream>>>(xs, s, c256);

    // slot 0: g_0 = B, h_0 = theta (exact fp32)
    hipMemcpyAsync(gv, B,     L_ * sizeof(float), hipMemcpyDeviceToDevice, stream);
    hipMemcpyAsync(hv, theta, L_ * sizeof(float), hipMemcpyDeviceToDevice, stream);

    if (fat) {
        // pass 0: fp32 A (nt, 16B loads), exact slot1, fused hi/lo quantized G write
        pass0_kernel<true><<<dim3(P0BLK), dim3(CT), 0, stream>>>(
            A, gv, hv, GHi, GLo, gv + L_, hv + L_);

        // fused passes 1..MPOW-1 in ONE cooperative kernel
        int pbeg = 1, pend = MPOW;
        void* args[] = { (void*)&GHi, (void*)&GLo, (void*)&gv, (void*)&hv,
                         (void*)&pbeg, (void*)&pend };
        hipError_t ce = hipLaunchCooperativeKernel((void*)chain_all,
                            dim3(CABLK), dim3(CT), args, 0, stream);
        if (ce != hipSuccess) {
            // fallback: per-pass normal launches (grid.sync skipped: pend==p+1)
            for (int p = 1; p < MPOW; ++p)
                chain_all<<<dim3(CABLK), dim3(CT), 0, stream>>>(GHi, GLo, gv, hv, p, p + 1);
        }
    } else {
        for (int p = 0; p < MPOW; ++p)
            pass0_kernel<false><<<dim3(P0BLK), dim3(CT), 0, stream>>>(A,
                gv + (size_t)p * L_,       hv + (size_t)p * L_,
                nullptr, nullptr,
                gv + (size_t)(p + 1) * L_, hv + (size_t)(p + 1) * L_);
    }

    combine_kernel<<<(L_ + 255) / 256, 256, 0, stream>>>(gv, hv, s, c256, pfin);
    mlp_kernel<<<dim3(8, 4), 64, 0, stream>>>(pfin, ts, out);
}

// Round 6
// 444.357 us; speedup vs baseline: 6.2443x; 6.2443x over previous
//
#include <hip/hip_runtime.h>

// ---------------- problem constants ----------------
#define L_      8838           // LATENT
#define LP_     9216           // padded row length (u8 bytes per G row; bf16 per LDS vec)
#define MPOW    8              // highest kept power of G (validated: absmax 0.125 @ R5)
#define NSLOT   (MPOW + 1)
#define NFULL   3              // passes 1..NFULL read hi+lo; later passes hi-only
#define CT      512            // threads per block (8 waves)
#define CWGRID  512            // chain grid (grid-stride over rows)
#define CWAVES  (CWGRID * (CT / 64))   // 4096
#define P0BLK   ((L_ + 7) / 8)         // 1105 blocks, one row per wave
#define P0DEPTH 12                     // pass0 load pipeline depth (16B each)

// quantization: q16 = clamp(rn((g + BOFF)/D16), 0, 65535), g = q16*D16 - BOFF
// hi = rn(q16/256) (unbiased hi-only recon), lo = q16 - 256*hi + 128
#define BOFF 6.0e-4f
#define D16  (BOFF / 32768.0f)
#define DHI  (BOFF / 128.0f)           // 256 * D16 ; 128*DHI == BOFF exactly
#define C2   (BOFF + 128.0f * D16)
#define QS   (32768.0f / BOFF)

typedef float          f32x4 __attribute__((ext_vector_type(4)));
typedef unsigned int   u32x4 __attribute__((ext_vector_type(4)));
typedef unsigned short us8   __attribute__((ext_vector_type(8)));
typedef unsigned short us4   __attribute__((ext_vector_type(4)));

__device__ __forceinline__ float bf2f(unsigned short u) {
    union { unsigned int i; float f; } x; x.i = ((unsigned int)u) << 16; return x.f;
}
__device__ __forceinline__ unsigned short f2bf(float f) {
    union { float f; unsigned int i; } x; x.f = f;
    unsigned int r = x.i + 0x7FFFu + ((x.i >> 16) & 1u);   // RNE
    return (unsigned short)(r >> 16);
}
__device__ __forceinline__ float ubf(unsigned int u, int b) {
    return (float)((u >> (8 * b)) & 255u);   // -> v_cvt_f32_ubyteN
}

// stage vectors to LDS as bf16 (36.9 KB total -> 4 blocks/CU)
__device__ __forceinline__ void stage_vec(const float* __restrict__ gin,
                                          const float* __restrict__ hin,
                                          unsigned short* sg, unsigned short* sh)
{
    #pragma unroll
    for (int k = 0; k < LP_ / CT; ++k) {   // 18
        const int j = k * CT + threadIdx.x;
        sg[j] = f2bf((j < L_) ? gin[j] : 0.f);
        sh[j] = f2bf((j < L_) ? hin[j] : 0.f);
    }
    __syncthreads();
}

__device__ __forceinline__ void quant4(const float x[4], int j0, int rdiag,
                                       unsigned int& hw, unsigned int& lw)
{
    hw = 0; lw = 0;
    #pragma unroll
    for (int e = 0; e < 4; ++e) {
        const float g = x[e] - ((j0 + e == rdiag) ? 1.f : 0.f);
        int q = __float2int_rn(fmaf(g, QS, 32768.0f));
        q = min(max(q, 0), 65535);
        const int h = min((q + 128) >> 8, 255);
        const int l = min(q - (h << 8) + 128, 255);
        hw |= (unsigned)h << (8 * e);
        lw |= (unsigned)l << (8 * e);
    }
}

// ---------------- full-precision chain pass (hi+lo, int16 fixed point) ----------------
template<bool PF>
__device__ __forceinline__ void full_row(const unsigned short* sg, const unsigned short* sh,
                                         int lane, u32x4 (&mh)[9], u32x4 (&ml)[9],
                                         const unsigned char* RnH, const unsigned char* RnL,
                                         float& ag, float& ah)
{
    #pragma unroll
    for (int c = 0; c < 9; ++c) {
        const u32x4 uh = mh[c], ul = ml[c];
        if constexpr (PF) {                       // prefetch next row into dead regs
            mh[c] = *(const u32x4*)(RnH + c * 1024);
            ml[c] = *(const u32x4*)(RnL + c * 1024);
        }
        const int j0 = c * 1024 + lane * 16;
        const us8 vg0 = *(const us8*)(sg + j0), vg1 = *(const us8*)(sg + j0 + 8);
        const us8 vh0 = *(const us8*)(sh + j0), vh1 = *(const us8*)(sh + j0 + 8);
        #pragma unroll
        for (int d = 0; d < 4; ++d) {
            #pragma unroll
            for (int b = 0; b < 4; ++b) {
                const int col = d * 4 + b;        // 0..15, compile-time
                const float v = fmaf(ubf(uh[d], b), DHI, fmaf(ubf(ul[d], b), D16, -C2));
                ag = fmaf(v, bf2f(col < 8 ? vg0[col] : vg1[col - 8]), ag);
                ah = fmaf(v, bf2f(col < 8 ? vh0[col] : vh1[col - 8]), ah);
            }
        }
    }
}

__global__ __launch_bounds__(CT)
void chain_full(const unsigned char* __restrict__ GHi, const unsigned char* __restrict__ GLo,
                const float* __restrict__ gin, const float* __restrict__ hin,
                float* __restrict__ gout, float* __restrict__ hout)
{
    __shared__ unsigned short sg[LP_], sh[LP_];
    stage_vec(gin, hin, sg, sh);
    const int lane = threadIdx.x & 63;
    int row = blockIdx.x * (CT / 64) + (threadIdx.x >> 6);

    u32x4 mh[9], ml[9];
    if (row < L_) {
        const unsigned char* RH = GHi + (size_t)row * LP_ + lane * 16;
        const unsigned char* RL = GLo + (size_t)row * LP_ + lane * 16;
        #pragma unroll
        for (int c = 0; c < 9; ++c) {
            mh[c] = *(const u32x4*)(RH + c * 1024);
            ml[c] = *(const u32x4*)(RL + c * 1024);
        }
    }
    while (row < L_) {
        const int nrow = row + CWAVES;
        const unsigned char* RnH = GHi + (size_t)nrow * LP_ + lane * 16;
        const unsigned char* RnL = GLo + (size_t)nrow * LP_ + lane * 16;
        float ag = 0.f, ah = 0.f;
        if (nrow < L_) full_row<true >(sg, sh, lane, mh, ml, RnH, RnL, ag, ah);
        else           full_row<false>(sg, sh, lane, mh, ml, RnH, RnL, ag, ah);
        #pragma unroll
        for (int o = 32; o; o >>= 1) { ag += __shfl_xor(ag, o); ah += __shfl_xor(ah, o); }
        if (lane == 0) { gout[row] = ag; hout[row] = ah; }
        row = nrow;
    }
}

// ---------------- hi-only chain pass (int8, 81 MB/pass) ----------------
template<bool PF>
__device__ __forceinline__ void hi_row(const unsigned short* sg, const unsigned short* sh,
                                       int lane, u32x4 (&mh)[9],
                                       const unsigned char* RnH,
                                       float& ag, float& ah)
{
    #pragma unroll
    for (int c = 0; c < 9; ++c) {
        const u32x4 uh = mh[c];
        if constexpr (PF) mh[c] = *(const u32x4*)(RnH + c * 1024);
        const int j0 = c * 1024 + lane * 16;
        const us8 vg0 = *(const us8*)(sg + j0), vg1 = *(const us8*)(sg + j0 + 8);
        const us8 vh0 = *(const us8*)(sh + j0), vh1 = *(const us8*)(sh + j0 + 8);
        #pragma unroll
        for (int d = 0; d < 4; ++d) {
            #pragma unroll
            for (int b = 0; b < 4; ++b) {
                const int col = d * 4 + b;
                const float v = fmaf(ubf(uh[d], b), DHI, -BOFF);
                ag = fmaf(v, bf2f(col < 8 ? vg0[col] : vg1[col - 8]), ag);
                ah = fmaf(v, bf2f(col < 8 ? vh0[col] : vh1[col - 8]), ah);
            }
        }
    }
}

__global__ __launch_bounds__(CT)
void chain_hi(const unsigned char* __restrict__ GHi,
              const float* __restrict__ gin, const float* __restrict__ hin,
              float* __restrict__ gout, float* __restrict__ hout)
{
    __shared__ unsigned short sg[LP_], sh[LP_];
    stage_vec(gin, hin, sg, sh);
    const int lane = threadIdx.x & 63;
    int row = blockIdx.x * (CT / 64) + (threadIdx.x >> 6);

    u32x4 mh[9];
    if (row < L_) {
        const unsigned char* RH = GHi + (size_t)row * LP_ + lane * 16;
        #pragma unroll
        for (int c = 0; c < 9; ++c) mh[c] = *(const u32x4*)(RH + c * 1024);
    }
    while (row < L_) {
        const int nrow = row + CWAVES;
        const unsigned char* RnH = GHi + (size_t)nrow * LP_ + lane * 16;
        float ag = 0.f, ah = 0.f;
        if (nrow < L_) hi_row<true >(sg, sh, lane, mh, RnH, ag, ah);
        else           hi_row<false>(sg, sh, lane, mh, RnH, ag, ah);
        #pragma unroll
        for (int o = 32; o; o >>= 1) { ag += __shfl_xor(ag, o); ah += __shfl_xor(ah, o); }
        if (lane == 0) { gout[row] = ag; hout[row] = ah; }
        row = nrow;
    }
}

// ---------------- pass 0: fp32 A, exact (A-I)*v, fused hi/lo quantized write ----------------
// One row per wave, 12-deep statically-indexed load pipeline (12 x 16B nt in flight).
template<bool WRITE_G>
__global__ __launch_bounds__(CT)
void pass0_kernel(const float* __restrict__ A,
                  const float* __restrict__ gin, const float* __restrict__ hin,
                  unsigned char* __restrict__ GHi, unsigned char* __restrict__ GLo,
                  float* __restrict__ gout, float* __restrict__ hout)
{
    __shared__ unsigned short sg[LP_], sh[LP_];
    stage_vec(gin, hin, sg, sh);
    const int lane = threadIdx.x & 63;
    const int row = blockIdx.x * (CT / 64) + (threadIdx.x >> 6);
    if (row >= L_) return;
    const float* __restrict__ Arow = A + (size_t)row * L_;
    unsigned char* __restrict__ WH = GHi + (size_t)row * LP_;
    unsigned char* __restrict__ WL = GLo + (size_t)row * LP_;

    float ag = 0.f, ah = 0.f;
    f32x4 buf[P0DEPTH];
    #pragma unroll
    for (int i = 0; i < P0DEPTH; ++i)
        buf[i] = __builtin_nontemporal_load((const f32x4*)(Arow + i * 256 + lane * 4));

    #pragma unroll   // full unroll: ring index it%P0DEPTH stays compile-time (no scratch)
    for (int it = 0; it < 34; ++it) {        // cols 0..8703 in full 16B chunks
        const int j0 = it * 256 + lane * 4;
        const f32x4 x = buf[it % P0DEPTH];
        if (it + P0DEPTH < 34)
            buf[it % P0DEPTH] = __builtin_nontemporal_load(
                (const f32x4*)(Arow + (it + P0DEPTH) * 256 + lane * 4));
        if constexpr (WRITE_G) {
            float y[4] = {x[0], x[1], x[2], x[3]};
            unsigned int hw, lw;
            quant4(y, j0, row, hw, lw);
            *(unsigned int*)(WH + j0) = hw;
            *(unsigned int*)(WL + j0) = lw;
        }
        const us4 vg = *(const us4*)(sg + j0);
        const us4 vh = *(const us4*)(sh + j0);
        #pragma unroll
        for (int e = 0; e < 4; ++e) {
            ag = fmaf(x[e], bf2f(vg[e]), ag);
            ah = fmaf(x[e], bf2f(vh[e]), ah);
        }
    }
    {   // tail iter (cols 8704..8837, guarded; OOB quantizes exact zero)
        const int j0 = 34 * 256 + lane * 4;
        float x[4];
        #pragma unroll
        for (int e = 0; e < 4; ++e) x[e] = (j0 + e < L_) ? Arow[j0 + e] : 0.f;
        if constexpr (WRITE_G) {
            unsigned int hw, lw;
            quant4(x, j0, row, hw, lw);
            *(unsigned int*)(WH + j0) = hw;
            *(unsigned int*)(WL + j0) = lw;
        }
        const us4 vg = *(const us4*)(sg + j0);   // zeros beyond L_
        const us4 vh = *(const us4*)(sh + j0);
        #pragma unroll
        for (int e = 0; e < 4; ++e) {
            ag = fmaf(x[e], bf2f(vg[e]), ag);
            ah = fmaf(x[e], bf2f(vh[e]), ah);
        }
    }
    #pragma unroll
    for (int o = 32; o; o >>= 1) { ag += __shfl_xor(ag, o); ah += __shfl_xor(ah, o); }
    if (lane == 0) {   // subtract the SAME rounded v[row] -> exact identity cancel
        gout[row] = ag - bf2f(sg[row]);
        hout[row] = ah - bf2f(sh[row]);
    }
}

// ---------------- binomial coefficients (fp64) ----------------
__global__ void coeff_kernel(const float* __restrict__ xs,
                             double* __restrict__ s, double* __restrict__ c256)
{
    const int lane = threadIdx.x;        // 64 threads
    const int t0 = lane * 4;
    float xl[8][4];
    #pragma unroll
    for (int b = 0; b < 8; ++b)
        #pragma unroll
        for (int i = 0; i < 4; ++i)
            xl[b][i] = xs[b * 256 + t0 + i];

    double c[4] = {1.0, 1.0, 1.0, 1.0};  // C(255-t, m), m starts at 0
    for (int m = 0; m <= MPOW; ++m) {
        #pragma unroll
        for (int b = 0; b < 8; ++b) {
            double part = c[0] * xl[b][0] + c[1] * xl[b][1]
                        + c[2] * xl[b][2] + c[3] * xl[b][3];
            for (int o = 32; o; o >>= 1) part += __shfl_xor(part, o);
            if (lane == 0) s[m * 8 + b] = part;
        }
        #pragma unroll
        for (int i = 0; i < 4; ++i) {
            double k = (double)(255 - (t0 + i));
            c[i] *= (k - m) / (double)(m + 1);   // -> C(k, m+1); 0 past m=k
        }
    }
    if (lane == 0) {
        double c2 = 1.0;
        for (int m = 0; m <= MPOW; ++m) { c256[m] = c2; c2 = c2 * (256.0 - m) / (double)(m + 1); }
    }
}

// ---------------- combine: p_final[b,i] ----------------
__global__ __launch_bounds__(256)
void combine_kernel(const float* __restrict__ gv, const float* __restrict__ hv,
                    const double* __restrict__ s, const double* __restrict__ c256,
                    float* __restrict__ pfin)
{
    int i = blockIdx.x * 256 + threadIdx.x;
    if (i >= L_) return;
    double acc[8] = {0, 0, 0, 0, 0, 0, 0, 0};
    double hs = 0.0;
    for (int m = 0; m <= MPOW; ++m) {
        double g = (double)gv[(size_t)m * L_ + i];
        double h = (double)hv[(size_t)m * L_ + i];
        hs += c256[m] * h;
        #pragma unroll
        for (int b = 0; b < 8; ++b) acc[b] += s[m * 8 + b] * g;
    }
    #pragma unroll
    for (int b = 0; b < 8; ++b)
        pfin[(size_t)b * L_ + i] = (float)(acc[b] + hs);
}

// ---------------- MLP evaluation ----------------
// weights p: W1[0:64] b1[64:128] W2[128:4224] b2[4224:4288]
//            W3[4288:8384] b3[8384:8448] W4[8448:8832] b4[8832:8838]
__global__ __launch_bounds__(64)
void mlp_kernel(const float* __restrict__ pfin, const float* __restrict__ ts,
                float* __restrict__ out)
{
    const int b = blockIdx.x;
    const int t = blockIdx.y * 64 + threadIdx.x;
    const float* __restrict__ p = pfin + (size_t)b * L_;   // uniform -> s_loads
    const float tv = ts[b * 256 + t];

    float h1[64], h2[64];
    #pragma unroll
    for (int o = 0; o < 64; ++o)
        h1[o] = fmaxf(fmaf(p[o], tv, p[64 + o]), 0.f);
    #pragma unroll
    for (int o = 0; o < 64; ++o) {
        float a0 = p[4224 + o], a1 = 0.f, a2 = 0.f, a3 = 0.f;
        #pragma unroll
        for (int d = 0; d < 64; d += 4) {
            a0 = fmaf(p[128 + o * 64 + d + 0], h1[d + 0], a0);
            a1 = fmaf(p[128 + o * 64 + d + 1], h1[d + 1], a1);
            a2 = fmaf(p[128 + o * 64 + d + 2], h1[d + 2], a2);
            a3 = fmaf(p[128 + o * 64 + d + 3], h1[d + 3], a3);
        }
        h2[o] = fmaxf((a0 + a1) + (a2 + a3), 0.f);
    }
    #pragma unroll
    for (int o = 0; o < 64; ++o) {
        float a0 = p[8384 + o], a1 = 0.f, a2 = 0.f, a3 = 0.f;
        #pragma unroll
        for (int d = 0; d < 64; d += 4) {
            a0 = fmaf(p[4288 + o * 64 + d + 0], h2[d + 0], a0);
            a1 = fmaf(p[4288 + o * 64 + d + 1], h2[d + 1], a1);
            a2 = fmaf(p[4288 + o * 64 + d + 2], h2[d + 2], a2);
            a3 = fmaf(p[4288 + o * 64 + d + 3], h2[d + 3], a3);
        }
        h1[o] = fmaxf((a0 + a1) + (a2 + a3), 0.f);   // reuse as h3
    }
    #pragma unroll
    for (int o = 0; o < 6; ++o) {
        float a0 = p[8832 + o], a1 = 0.f, a2 = 0.f, a3 = 0.f;
        #pragma unroll
        for (int d = 0; d < 64; d += 4) {
            a0 = fmaf(p[8448 + o * 64 + d + 0], h1[d + 0], a0);
            a1 = fmaf(p[8448 + o * 64 + d + 1], h1[d + 1], a1);
            a2 = fmaf(p[8448 + o * 64 + d + 2], h1[d + 2], a2);
            a3 = fmaf(p[8448 + o * 64 + d + 3], h1[d + 3], a3);
        }
        out[((size_t)(b * 256 + t)) * 6 + o] = (a0 + a1) + (a2 + a3);
    }
}

// ---------------- host launcher ----------------
extern "C" void kernel_launch(void* const* d_in, const int* in_sizes, int n_in,
                              void* d_out, int out_size, void* d_ws, size_t ws_size,
                              hipStream_t stream)
{
    const float* xs    = (const float*)d_in[0];  // (8,1,256,1)
    const float* ts    = (const float*)d_in[1];  // (8,256)
    const float* theta = (const float*)d_in[2];  // (8838,)
    const float* A     = (const float*)d_in[3];  // (8838,8838)
    const float* B     = (const float*)d_in[4];  // (8838,1)
    float* out = (float*)d_out;

    const size_t GB1 = (size_t)L_ * LP_;                          // 81,451,008 per array
    const size_t VB  = (size_t)NSLOT * L_ * sizeof(float);
    const size_t SB  = (size_t)NSLOT * 8 * sizeof(double);
    const size_t CB  = 256;                                       // c256 (padded)
    const size_t PB  = (size_t)8 * L_ * sizeof(float);
    const size_t SMALL = 2 * VB + SB + CB + PB;
    const size_t FULL  = 2 * GB1 + SMALL;

    if (ws_size < SMALL) return;   // cannot run; fail loudly via validation
    const bool fat = (ws_size >= FULL);

    char* base = (char*)d_ws;
    unsigned char* GHi = (unsigned char*)base;
    unsigned char* GLo = (unsigned char*)(base + GB1);
    size_t off = fat ? 2 * GB1 : 0;
    float*  gv   = (float*)(base + off);  off += VB;
    float*  hv   = (float*)(base + off);  off += VB;
    double* s    = (double*)(base + off); off += SB;
    double* c256 = (double*)(base + off); off += CB;
    float*  pfin = (float*)(base + off);

    // independent of chain -> launch first
    coeff_kernel<<<1, 64, 0, stream>>>(xs, s, c256);

    // slot 0: g_0 = B, h_0 = theta (exact fp32)
    hipMemcpyAsync(gv, B,     L_ * sizeof(float), hipMemcpyDeviceToDevice, stream);
    hipMemcpyAsync(hv, theta, L_ * sizeof(float), hipMemcpyDeviceToDevice, stream);

    if (fat) {
        // pass 0: fp32 A (nt, 12-deep 16B pipeline), exact slot1, fused hi/lo G write
        pass0_kernel<true><<<dim3(P0BLK), dim3(CT), 0, stream>>>(
            A, gv, hv, GHi, GLo, gv + L_, hv + L_);
        for (int p = 1; p < MPOW; ++p) {
            const float* gi = gv + (size_t)p * L_;
            const float* hi = hv + (size_t)p * L_;
            float* go = gv + (size_t)(p + 1) * L_;
            float* ho = hv + (size_t)(p + 1) * L_;
            if (p <= NFULL)
                chain_full<<<dim3(CWGRID), dim3(CT), 0, stream>>>(GHi, GLo, gi, hi, go, ho);
            else
                chain_hi<<<dim3(CWGRID), dim3(CT), 0, stream>>>(GHi, gi, hi, go, ho);
        }
    } else {
        for (int p = 0; p < MPOW; ++p)
            pass0_kernel<false><<<dim3(P0BLK), dim3(CT), 0, stream>>>(A,
                gv + (size_t)p * L_,       hv + (size_t)p * L_,
                nullptr, nullptr,
                gv + (size_t)(p + 1) * L_, hv + (size_t)(p + 1) * L_);
    }

    combine_kernel<<<(L_ + 255) / 256, 256, 0, stream>>>(gv, hv, s, c256, pfin);
    mlp_kernel<<<dim3(8, 4), 64, 0, stream>>>(pfin, ts, out);
}